// Round 1
// baseline (2814.198 us; speedup 1.0000x reference)
//
#include <hip/hip_runtime.h>
#include <hip/hip_bf16.h>

#define B_SZ 4
#define L_SZ 512
#define D_MODEL 256
#define D_INNER 512
#define D_STATE 16
#define DT_RANK 16
#define N_LAYERS 6
#define BL (B_SZ * L_SZ)   // 2048 token rows

// ---------------------------------------------------------------------------
// RMSNorm: one wave (64 lanes) per row of 256; 4 rows per 256-thread block.
// ---------------------------------------------------------------------------
__global__ __launch_bounds__(256) void rmsnorm_kernel(
    const float* __restrict__ x, const float* __restrict__ w,
    float* __restrict__ o)
{
    int row  = blockIdx.x * 4 + (threadIdx.x >> 6);
    int lane = threadIdx.x & 63;
    const float4 v = *(const float4*)(x + (size_t)row * D_MODEL + lane * 4);
    float ss = v.x * v.x + v.y * v.y + v.z * v.z + v.w * v.w;
    #pragma unroll
    for (int off = 32; off; off >>= 1) ss += __shfl_xor(ss, off);
    float rs = rsqrtf(ss * (1.f / D_MODEL) + 1e-5f);
    const float4 wv = *(const float4*)(w + lane * 4);
    float4 ov;
    ov.x = v.x * rs * wv.x;
    ov.y = v.y * rs * wv.y;
    ov.z = v.z * rs * wv.z;
    ov.w = v.w * rs * wv.w;
    *(float4*)(o + (size_t)row * D_MODEL + lane * 4) = ov;
}

// ---------------------------------------------------------------------------
// Generic fp32 NT GEMM: C[M,N] = A[M,K] @ B[N,K]^T (+bias) (+residual) (+act)
// A row stride lda, B row stride ldb (both K-contiguous). 256 threads.
// ACT: 0 = none, 1 = softplus (for delta).
// M assumed divisible by BM; N guarded; K divisible by BK; lda/ldb %4 == 0.
// ---------------------------------------------------------------------------
template<int BM, int BN, int BK, int TM, int TN, int ACT>
__global__ __launch_bounds__(256) void gemm_nt(
    const float* __restrict__ A, int lda,
    const float* __restrict__ Bm, int ldb,
    const float* __restrict__ bias,
    const float* __restrict__ R, int ldr,
    float* __restrict__ C, int ldc,
    int M, int N, int K)
{
    __shared__ float As[BK][BM + 4];
    __shared__ float Bs[BK][BN + 4];
    constexpr int TX = BN / TN;
    constexpr int TY = BM / TM;
    static_assert(TX * TY == 256, "thread layout");
    const int tid = threadIdx.x;
    const int tx = tid % TX, ty = tid / TX;
    const int m0 = blockIdx.y * BM, n0 = blockIdx.x * BN;

    float acc[TM][TN] = {};

    for (int k0 = 0; k0 < K; k0 += BK) {
        constexpr int AV = BM * BK / 4;
        #pragma unroll
        for (int idx = tid; idx < AV; idx += 256) {
            int r = idx / (BK / 4);
            int c = (idx % (BK / 4)) * 4;
            float4 v = *(const float4*)(A + (size_t)(m0 + r) * lda + k0 + c);
            As[c + 0][r] = v.x; As[c + 1][r] = v.y;
            As[c + 2][r] = v.z; As[c + 3][r] = v.w;
        }
        constexpr int BV = BN * BK / 4;
        #pragma unroll
        for (int idx = tid; idx < BV; idx += 256) {
            int r = idx / (BK / 4);
            int c = (idx % (BK / 4)) * 4;
            float4 v = make_float4(0.f, 0.f, 0.f, 0.f);
            if (n0 + r < N)
                v = *(const float4*)(Bm + (size_t)(n0 + r) * ldb + k0 + c);
            Bs[c + 0][r] = v.x; Bs[c + 1][r] = v.y;
            Bs[c + 2][r] = v.z; Bs[c + 3][r] = v.w;
        }
        __syncthreads();
        #pragma unroll
        for (int k = 0; k < BK; ++k) {
            float am[TM], bn[TN];
            #pragma unroll
            for (int i = 0; i < TM; i++) am[i] = As[k][ty * TM + i];
            #pragma unroll
            for (int j = 0; j < TN; j++) bn[j] = Bs[k][tx * TN + j];
            #pragma unroll
            for (int i = 0; i < TM; i++)
                #pragma unroll
                for (int j = 0; j < TN; j++)
                    acc[i][j] += am[i] * bn[j];
        }
        __syncthreads();
    }

    #pragma unroll
    for (int i = 0; i < TM; i++) {
        int m = m0 + ty * TM + i;
        #pragma unroll
        for (int j = 0; j < TN; j++) {
            int n = n0 + tx * TN + j;
            if (n < N) {
                float v = acc[i][j];
                if (bias) v += bias[n];
                if (R)    v += R[(size_t)m * ldr + n];
                if (ACT == 1) v = (v > 20.f) ? v : log1pf(__expf(v));
                C[(size_t)m * ldc + n] = v;
            }
        }
    }
}

// ---------------------------------------------------------------------------
// Depthwise causal conv (width 4) + SiLU. xin = xz[..., 0:512].
// One thread per (b, t, d); d innermost -> coalesced.
// ---------------------------------------------------------------------------
__global__ __launch_bounds__(256) void conv_silu_kernel(
    const float* __restrict__ xz, const float* __restrict__ cw,
    float* __restrict__ u)
{
    int idx = blockIdx.x * 256 + threadIdx.x;   // (b*L + t)*512 + d
    int d  = idx & (D_INNER - 1);
    int bt = idx >> 9;
    int t  = bt & (L_SZ - 1);
    const float4 wv = *(const float4*)(cw + d * 4);
    const float* base = xz + (size_t)bt * (2 * D_INNER) + d;
    float acc = wv.w * base[0];
    if (t >= 1) acc += wv.z * base[-(2 * D_INNER)];
    if (t >= 2) acc += wv.y * base[-(4 * D_INNER)];
    if (t >= 3) acc += wv.x * base[-(6 * D_INNER)];
    u[idx] = acc / (1.f + __expf(-acc));
}

// ---------------------------------------------------------------------------
// Selective scan. One wave per (b, 4 channels): lane = 16*(d-sub) + n.
// h-recurrence is the only serial chain; exp/loads pipeline across t.
// Writes y[b,t,d] = (sum_n h*C + u*D) * silu(z).
// ---------------------------------------------------------------------------
__global__ __launch_bounds__(64) void scan_kernel(
    const float* __restrict__ xdbc,   // (BL, 48): [dt | B | C]
    const float* __restrict__ delta,  // (BL, 512)
    const float* __restrict__ u,      // (BL, 512)
    const float* __restrict__ xz,     // (BL, 1024); z at +512
    const float* __restrict__ A_log,  // (512, 16)
    const float* __restrict__ Dv,     // (512)
    float* __restrict__ y)            // (BL, 512)
{
    int wave = blockIdx.x;            // 512 waves total
    int lane = threadIdx.x & 63;
    int b  = wave >> 7;               // 128 waves per batch
    int dg = wave & 127;
    int d  = dg * 4 + (lane >> 4);
    int n  = lane & 15;

    float Adn = -__expf(A_log[d * D_STATE + n]);
    float Dd  = Dv[d];
    float h   = 0.f;
    size_t base = (size_t)b * L_SZ;

    #pragma unroll 4
    for (int t = 0; t < L_SZ; ++t) {
        size_t row = base + t;
        float Bv = xdbc[row * 48 + DT_RANK + n];
        float Cv = xdbc[row * 48 + DT_RANK + D_STATE + n];
        float dl = delta[row * D_INNER + d];
        float uv = u[row * D_INNER + d];
        float dA = __expf(dl * Adn);
        h = dA * h + dl * uv * Bv;
        float py = h * Cv;
        py += __shfl_xor(py, 8);
        py += __shfl_xor(py, 4);
        py += __shfl_xor(py, 2);
        py += __shfl_xor(py, 1);
        if (n == 0) {
            float zv = xz[row * (2 * D_INNER) + D_INNER + d];
            float sz = zv / (1.f + __expf(-zv));
            y[row * D_INNER + d] = (py + uv * Dd) * sz;
        }
    }
}

// ---------------------------------------------------------------------------
extern "C" void kernel_launch(void* const* d_in, const int* in_sizes, int n_in,
                              void* d_out, int out_size, void* d_ws, size_t ws_size,
                              hipStream_t stream)
{
    const float* x_in   = (const float*)d_in[0];
    const float* norm_w = (const float*)d_in[1];
    const float* W_in   = (const float*)d_in[2];
    const float* b_in   = (const float*)d_in[3];
    const float* conv_w = (const float*)d_in[4];
    const float* W_x    = (const float*)d_in[5];
    const float* dt_w   = (const float*)d_in[6];
    const float* dt_b   = (const float*)d_in[7];
    const float* A_log  = (const float*)d_in[8];
    const float* Dv     = (const float*)d_in[9];
    const float* W_out  = (const float*)d_in[10];
    const float* b_out  = (const float*)d_in[11];
    float* out = (float*)d_out;

    float* ws    = (float*)d_ws;
    float* xn    = ws;                      // 2048*256
    float* xz    = xn    + BL * D_MODEL;    // 2048*1024
    float* u     = xz    + BL * 2 * D_INNER;// 2048*512
    float* xdbc  = u     + BL * D_INNER;    // 2048*48
    float* delta = xdbc  + BL * 48;         // 2048*512
    float* y     = delta + BL * D_INNER;    // 2048*512

    for (int i = 0; i < N_LAYERS; ++i) {
        const float* xcur = (i == 0) ? x_in : out;

        rmsnorm_kernel<<<BL / 4, 256, 0, stream>>>(xcur, norm_w + i * D_MODEL, xn);

        // xz = xn @ W_in^T + b_in   (M=2048, N=1024, K=256)
        gemm_nt<64, 64, 16, 4, 4, 0><<<dim3(16, 32), 256, 0, stream>>>(
            xn, D_MODEL, W_in + (size_t)i * 2 * D_INNER * D_MODEL, D_MODEL,
            b_in + i * 2 * D_INNER, nullptr, 0, xz, 2 * D_INNER,
            BL, 2 * D_INNER, D_MODEL);

        conv_silu_kernel<<<BL * D_INNER / 256, 256, 0, stream>>>(
            xz, conv_w + i * D_INNER * 4, u);

        // xdbc = u @ W_x^T          (M=2048, N=48, K=512)
        gemm_nt<64, 16, 16, 4, 1, 0><<<dim3(3, 32), 256, 0, stream>>>(
            u, D_INNER, W_x + (size_t)i * 48 * D_INNER, D_INNER,
            nullptr, nullptr, 0, xdbc, 48,
            BL, 48, D_INNER);

        // delta = softplus(dt @ dt_w^T + dt_b)  (M=2048, N=512, K=16)
        gemm_nt<64, 64, 16, 4, 4, 1><<<dim3(8, 32), 256, 0, stream>>>(
            xdbc, 48, dt_w + (size_t)i * D_INNER * DT_RANK, DT_RANK,
            dt_b + i * D_INNER, nullptr, 0, delta, D_INNER,
            BL, D_INNER, DT_RANK);

        scan_kernel<<<512, 64, 0, stream>>>(
            xdbc, delta, u, xz,
            A_log + (size_t)i * D_INNER * D_STATE, Dv + i * D_INNER, y);

        // out = xcur + y @ W_out^T + b_out  (M=2048, N=256, K=512)
        gemm_nt<64, 64, 16, 4, 4, 0><<<dim3(4, 32), 256, 0, stream>>>(
            y, D_INNER, W_out + (size_t)i * D_MODEL * D_INNER, D_INNER,
            b_out + i * D_MODEL, xcur, D_MODEL, out, D_MODEL,
            BL, D_MODEL, D_INNER);
    }
}

// Round 2
// 1282.299 us; speedup vs baseline: 2.1947x; 2.1947x over previous
//
#include <hip/hip_runtime.h>
#include <hip/hip_bf16.h>

#define B_SZ 4
#define L_SZ 512
#define D_MODEL 256
#define D_INNER 512
#define D_STATE 16
#define DT_RANK 16
#define N_LAYERS 6
#define BL (B_SZ * L_SZ)   // 2048 token rows

// ---------------------------------------------------------------------------
// RMSNorm: one wave (64 lanes) per row of 256; 4 rows per 256-thread block.
// ---------------------------------------------------------------------------
__global__ __launch_bounds__(256) void rmsnorm_kernel(
    const float* __restrict__ x, const float* __restrict__ w,
    float* __restrict__ o)
{
    int row  = blockIdx.x * 4 + (threadIdx.x >> 6);
    int lane = threadIdx.x & 63;
    const float4 v = *(const float4*)(x + (size_t)row * D_MODEL + lane * 4);
    float ss = v.x * v.x + v.y * v.y + v.z * v.z + v.w * v.w;
    #pragma unroll
    for (int off = 32; off; off >>= 1) ss += __shfl_xor(ss, off);
    float rs = rsqrtf(ss * (1.f / D_MODEL) + 1e-5f);
    const float4 wv = *(const float4*)(w + lane * 4);
    float4 ov;
    ov.x = v.x * rs * wv.x;
    ov.y = v.y * rs * wv.y;
    ov.z = v.z * rs * wv.z;
    ov.w = v.w * rs * wv.w;
    *(float4*)(o + (size_t)row * D_MODEL + lane * 4) = ov;
}

// ---------------------------------------------------------------------------
// Generic fp32 NT GEMM: C[M,N] = A[M,K] @ B[N,K]^T (+bias) (+residual) (+act)
// ---------------------------------------------------------------------------
template<int BM, int BN, int BK, int TM, int TN, int ACT>
__global__ __launch_bounds__(256) void gemm_nt(
    const float* __restrict__ A, int lda,
    const float* __restrict__ Bm, int ldb,
    const float* __restrict__ bias,
    const float* __restrict__ R, int ldr,
    float* __restrict__ C, int ldc,
    int M, int N, int K)
{
    __shared__ float As[BK][BM + 4];
    __shared__ float Bs[BK][BN + 4];
    constexpr int TX = BN / TN;
    constexpr int TY = BM / TM;
    static_assert(TX * TY == 256, "thread layout");
    const int tid = threadIdx.x;
    const int tx = tid % TX, ty = tid / TX;
    const int m0 = blockIdx.y * BM, n0 = blockIdx.x * BN;

    float acc[TM][TN] = {};

    for (int k0 = 0; k0 < K; k0 += BK) {
        constexpr int AV = BM * BK / 4;
        #pragma unroll
        for (int idx = tid; idx < AV; idx += 256) {
            int r = idx / (BK / 4);
            int c = (idx % (BK / 4)) * 4;
            float4 v = *(const float4*)(A + (size_t)(m0 + r) * lda + k0 + c);
            As[c + 0][r] = v.x; As[c + 1][r] = v.y;
            As[c + 2][r] = v.z; As[c + 3][r] = v.w;
        }
        constexpr int BV = BN * BK / 4;
        #pragma unroll
        for (int idx = tid; idx < BV; idx += 256) {
            int r = idx / (BK / 4);
            int c = (idx % (BK / 4)) * 4;
            float4 v = make_float4(0.f, 0.f, 0.f, 0.f);
            if (n0 + r < N)
                v = *(const float4*)(Bm + (size_t)(n0 + r) * ldb + k0 + c);
            Bs[c + 0][r] = v.x; Bs[c + 1][r] = v.y;
            Bs[c + 2][r] = v.z; Bs[c + 3][r] = v.w;
        }
        __syncthreads();
        #pragma unroll
        for (int k = 0; k < BK; ++k) {
            float am[TM], bn[TN];
            #pragma unroll
            for (int i = 0; i < TM; i++) am[i] = As[k][ty * TM + i];
            #pragma unroll
            for (int j = 0; j < TN; j++) bn[j] = Bs[k][tx * TN + j];
            #pragma unroll
            for (int i = 0; i < TM; i++)
                #pragma unroll
                for (int j = 0; j < TN; j++)
                    acc[i][j] += am[i] * bn[j];
        }
        __syncthreads();
    }

    #pragma unroll
    for (int i = 0; i < TM; i++) {
        int m = m0 + ty * TM + i;
        #pragma unroll
        for (int j = 0; j < TN; j++) {
            int n = n0 + tx * TN + j;
            if (n < N) {
                float v = acc[i][j];
                if (bias) v += bias[n];
                if (R)    v += R[(size_t)m * ldr + n];
                if (ACT == 1) v = (v > 20.f) ? v : log1pf(__expf(v));
                C[(size_t)m * ldc + n] = v;
            }
        }
    }
}

// ---------------------------------------------------------------------------
// Depthwise causal conv (width 4) + SiLU.
// ---------------------------------------------------------------------------
__global__ __launch_bounds__(256) void conv_silu_kernel(
    const float* __restrict__ xz, const float* __restrict__ cw,
    float* __restrict__ u)
{
    int idx = blockIdx.x * 256 + threadIdx.x;   // (b*L + t)*512 + d
    int d  = idx & (D_INNER - 1);
    int bt = idx >> 9;
    int t  = bt & (L_SZ - 1);
    const float4 wv = *(const float4*)(cw + d * 4);
    const float* base = xz + (size_t)bt * (2 * D_INNER) + d;
    float acc = wv.w * base[0];
    if (t >= 1) acc += wv.z * base[-(2 * D_INNER)];
    if (t >= 2) acc += wv.y * base[-(4 * D_INNER)];
    if (t >= 3) acc += wv.x * base[-(6 * D_INNER)];
    u[idx] = acc / (1.f + __expf(-acc));
}

// ---------------------------------------------------------------------------
// Selective scan, chunked-phase version.
// One wave per (b, 4 channels): lane = 16*(d-sub) + n.
// Per 32-step chunk:
//   phase 1: 32 independent load+exp+mul groups -> dA/dBu/Cv register arrays
//            (all loads in flight together; nothing depends on h)
//   phase 2: tight 32-FMA h-recurrence (the only true serial chain)
//   phase 3: 32 independent 4-shuffle reductions (pipeline across t)
//   phase 4: masked store phase (n==0 lanes), z-silu + u*D epilogue
// ---------------------------------------------------------------------------
__global__ __launch_bounds__(64) void scan_kernel(
    const float* __restrict__ xdbc,   // (BL, 48): [dt | B | C]
    const float* __restrict__ delta,  // (BL, 512)
    const float* __restrict__ u,      // (BL, 512)
    const float* __restrict__ xz,     // (BL, 1024); z at +512
    const float* __restrict__ A_log,  // (512, 16)
    const float* __restrict__ Dv,     // (512)
    float* __restrict__ y)            // (BL, 512)
{
    constexpr int T = 32;
    int wave = blockIdx.x;            // 512 waves total
    int lane = threadIdx.x & 63;
    int b  = wave >> 7;               // 128 waves per batch
    int dg = wave & 127;
    int d  = dg * 4 + (lane >> 4);
    int n  = lane & 15;

    float Adn = -__expf(A_log[d * D_STATE + n]);
    float Dd  = Dv[d];
    float h   = 0.f;
    size_t base = (size_t)b * L_SZ;

    for (int t0 = 0; t0 < L_SZ; t0 += T) {
        float dA[T], dBu[T], Cv[T], py[T];

        #pragma unroll
        for (int j = 0; j < T; ++j) {
            size_t row = base + t0 + j;
            float Bv = xdbc[row * 48 + DT_RANK + n];
            Cv[j]    = xdbc[row * 48 + DT_RANK + D_STATE + n];
            float dl = delta[row * D_INNER + d];
            float uv = u[row * D_INNER + d];
            dA[j]  = __expf(dl * Adn);
            dBu[j] = dl * uv * Bv;
        }

        #pragma unroll
        for (int j = 0; j < T; ++j) {
            h = dA[j] * h + dBu[j];
            py[j] = h * Cv[j];
        }

        #pragma unroll
        for (int j = 0; j < T; ++j) {
            float s = py[j];
            s += __shfl_xor(s, 8);
            s += __shfl_xor(s, 4);
            s += __shfl_xor(s, 2);
            s += __shfl_xor(s, 1);
            py[j] = s;
        }

        if (n == 0) {
            #pragma unroll
            for (int j = 0; j < T; ++j) {
                size_t row = base + t0 + j;
                float uv = u[row * D_INNER + d];
                float zv = xz[row * (2 * D_INNER) + D_INNER + d];
                float sz = zv / (1.f + __expf(-zv));
                y[row * D_INNER + d] = (py[j] + uv * Dd) * sz;
            }
        }
    }
}

// ---------------------------------------------------------------------------
extern "C" void kernel_launch(void* const* d_in, const int* in_sizes, int n_in,
                              void* d_out, int out_size, void* d_ws, size_t ws_size,
                              hipStream_t stream)
{
    const float* x_in   = (const float*)d_in[0];
    const float* norm_w = (const float*)d_in[1];
    const float* W_in   = (const float*)d_in[2];
    const float* b_in   = (const float*)d_in[3];
    const float* conv_w = (const float*)d_in[4];
    const float* W_x    = (const float*)d_in[5];
    const float* dt_w   = (const float*)d_in[6];
    const float* dt_b   = (const float*)d_in[7];
    const float* A_log  = (const float*)d_in[8];
    const float* Dv     = (const float*)d_in[9];
    const float* W_out  = (const float*)d_in[10];
    const float* b_out  = (const float*)d_in[11];
    float* out = (float*)d_out;

    float* ws    = (float*)d_ws;
    float* xn    = ws;                      // 2048*256
    float* xz    = xn    + BL * D_MODEL;    // 2048*1024
    float* u     = xz    + BL * 2 * D_INNER;// 2048*512
    float* xdbc  = u     + BL * D_INNER;    // 2048*48
    float* delta = xdbc  + BL * 48;         // 2048*512
    float* y     = delta + BL * D_INNER;    // 2048*512

    for (int i = 0; i < N_LAYERS; ++i) {
        const float* xcur = (i == 0) ? x_in : out;

        rmsnorm_kernel<<<BL / 4, 256, 0, stream>>>(xcur, norm_w + i * D_MODEL, xn);

        // xz = xn @ W_in^T + b_in   (M=2048, N=1024, K=256)
        gemm_nt<64, 64, 16, 4, 4, 0><<<dim3(16, 32), 256, 0, stream>>>(
            xn, D_MODEL, W_in + (size_t)i * 2 * D_INNER * D_MODEL, D_MODEL,
            b_in + i * 2 * D_INNER, nullptr, 0, xz, 2 * D_INNER,
            BL, 2 * D_INNER, D_MODEL);

        conv_silu_kernel<<<BL * D_INNER / 256, 256, 0, stream>>>(
            xz, conv_w + i * D_INNER * 4, u);

        // xdbc = u @ W_x^T          (M=2048, N=48, K=512)
        gemm_nt<64, 16, 16, 4, 1, 0><<<dim3(3, 32), 256, 0, stream>>>(
            u, D_INNER, W_x + (size_t)i * 48 * D_INNER, D_INNER,
            nullptr, nullptr, 0, xdbc, 48,
            BL, 48, D_INNER);

        // delta = softplus(dt @ dt_w^T + dt_b)  (M=2048, N=512, K=16)
        gemm_nt<64, 64, 16, 4, 4, 1><<<dim3(8, 32), 256, 0, stream>>>(
            xdbc, 48, dt_w + (size_t)i * D_INNER * DT_RANK, DT_RANK,
            dt_b + i * D_INNER, nullptr, 0, delta, D_INNER,
            BL, D_INNER, DT_RANK);

        scan_kernel<<<512, 64, 0, stream>>>(
            xdbc, delta, u, xz,
            A_log + (size_t)i * D_INNER * D_STATE, Dv + i * D_INNER, y);

        // out = xcur + y @ W_out^T + b_out  (M=2048, N=256, K=512)
        gemm_nt<64, 64, 16, 4, 4, 0><<<dim3(4, 32), 256, 0, stream>>>(
            y, D_INNER, W_out + (size_t)i * D_MODEL * D_INNER, D_INNER,
            b_out + i * D_MODEL, xcur, D_MODEL, out, D_MODEL,
            BL, D_MODEL, D_INNER);
    }
}

// Round 3
// 930.758 us; speedup vs baseline: 3.0236x; 1.3777x over previous
//
#include <hip/hip_runtime.h>
#include <hip/hip_bf16.h>

#define B_SZ 4
#define L_SZ 512
#define D_MODEL 256
#define D_INNER 512
#define D_STATE 16
#define DT_RANK 16
#define N_LAYERS 6
#define BL (B_SZ * L_SZ)   // 2048 token rows

// ---------------------------------------------------------------------------
// RMSNorm: one wave (64 lanes) per row of 256; 4 rows per 256-thread block.
// ---------------------------------------------------------------------------
__global__ __launch_bounds__(256) void rmsnorm_kernel(
    const float* __restrict__ x, const float* __restrict__ w,
    float* __restrict__ o)
{
    int row  = blockIdx.x * 4 + (threadIdx.x >> 6);
    int lane = threadIdx.x & 63;
    const float4 v = *(const float4*)(x + (size_t)row * D_MODEL + lane * 4);
    float ss = v.x * v.x + v.y * v.y + v.z * v.z + v.w * v.w;
    #pragma unroll
    for (int off = 32; off; off >>= 1) ss += __shfl_xor(ss, off);
    float rs = rsqrtf(ss * (1.f / D_MODEL) + 1e-5f);
    const float4 wv = *(const float4*)(w + lane * 4);
    float4 ov;
    ov.x = v.x * rs * wv.x;
    ov.y = v.y * rs * wv.y;
    ov.z = v.z * rs * wv.z;
    ov.w = v.w * rs * wv.w;
    *(float4*)(o + (size_t)row * D_MODEL + lane * 4) = ov;
}

// ---------------------------------------------------------------------------
// Generic fp32 NT GEMM: C[M,N] = A[M,K] @ B[N,K]^T (+bias) (+residual) (+act)
// ---------------------------------------------------------------------------
template<int BM, int BN, int BK, int TM, int TN, int ACT>
__global__ __launch_bounds__(256) void gemm_nt(
    const float* __restrict__ A, int lda,
    const float* __restrict__ Bm, int ldb,
    const float* __restrict__ bias,
    const float* __restrict__ R, int ldr,
    float* __restrict__ C, int ldc,
    int M, int N, int K)
{
    __shared__ float As[BK][BM + 4];
    __shared__ float Bs[BK][BN + 4];
    constexpr int TX = BN / TN;
    constexpr int TY = BM / TM;
    static_assert(TX * TY == 256, "thread layout");
    const int tid = threadIdx.x;
    const int tx = tid % TX, ty = tid / TX;
    const int m0 = blockIdx.y * BM, n0 = blockIdx.x * BN;

    float acc[TM][TN] = {};

    for (int k0 = 0; k0 < K; k0 += BK) {
        constexpr int AV = BM * BK / 4;
        #pragma unroll
        for (int idx = tid; idx < AV; idx += 256) {
            int r = idx / (BK / 4);
            int c = (idx % (BK / 4)) * 4;
            float4 v = *(const float4*)(A + (size_t)(m0 + r) * lda + k0 + c);
            As[c + 0][r] = v.x; As[c + 1][r] = v.y;
            As[c + 2][r] = v.z; As[c + 3][r] = v.w;
        }
        constexpr int BV = BN * BK / 4;
        #pragma unroll
        for (int idx = tid; idx < BV; idx += 256) {
            int r = idx / (BK / 4);
            int c = (idx % (BK / 4)) * 4;
            float4 v = make_float4(0.f, 0.f, 0.f, 0.f);
            if (n0 + r < N)
                v = *(const float4*)(Bm + (size_t)(n0 + r) * ldb + k0 + c);
            Bs[c + 0][r] = v.x; Bs[c + 1][r] = v.y;
            Bs[c + 2][r] = v.z; Bs[c + 3][r] = v.w;
        }
        __syncthreads();
        #pragma unroll
        for (int k = 0; k < BK; ++k) {
            float am[TM], bn[TN];
            #pragma unroll
            for (int i = 0; i < TM; i++) am[i] = As[k][ty * TM + i];
            #pragma unroll
            for (int j = 0; j < TN; j++) bn[j] = Bs[k][tx * TN + j];
            #pragma unroll
            for (int i = 0; i < TM; i++)
                #pragma unroll
                for (int j = 0; j < TN; j++)
                    acc[i][j] += am[i] * bn[j];
        }
        __syncthreads();
    }

    #pragma unroll
    for (int i = 0; i < TM; i++) {
        int m = m0 + ty * TM + i;
        #pragma unroll
        for (int j = 0; j < TN; j++) {
            int n = n0 + tx * TN + j;
            if (n < N) {
                float v = acc[i][j];
                if (bias) v += bias[n];
                if (R)    v += R[(size_t)m * ldr + n];
                if (ACT == 1) v = (v > 20.f) ? v : log1pf(__expf(v));
                C[(size_t)m * ldc + n] = v;
            }
        }
    }
}

// ---------------------------------------------------------------------------
// Depthwise causal conv (width 4) + SiLU.
// ---------------------------------------------------------------------------
__global__ __launch_bounds__(256) void conv_silu_kernel(
    const float* __restrict__ xz, const float* __restrict__ cw,
    float* __restrict__ u)
{
    int idx = blockIdx.x * 256 + threadIdx.x;   // (b*L + t)*512 + d
    int d  = idx & (D_INNER - 1);
    int bt = idx >> 9;
    int t  = bt & (L_SZ - 1);
    const float4 wv = *(const float4*)(cw + d * 4);
    const float* base = xz + (size_t)bt * (2 * D_INNER) + d;
    float acc = wv.w * base[0];
    if (t >= 1) acc += wv.z * base[-(2 * D_INNER)];
    if (t >= 2) acc += wv.y * base[-(4 * D_INNER)];
    if (t >= 3) acc += wv.x * base[-(6 * D_INNER)];
    u[idx] = acc / (1.f + __expf(-acc));
}

// ---------------------------------------------------------------------------
// Selective scan, time-parallel block-chunked version.
// Block = 512 threads = 8 waves, covering one (b, d-group of 4).
// Wave w owns time chunk [w*64, (w+1)*64). Lane = 16*(d-sub) + n.
// The recurrence h' = dA*h + dBu is affine, so each chunk with h0=0 yields
// (Ap = prod dA, h_end) with H_out = Ap*H_in + h_end. Pass 1 computes these
// locally, an LDS combine gives each wave its true incoming state H, pass 2
// re-runs the chunk from H and emits y. Inside each pass, sub-chunks of 16
// use the phase-split (batched loads -> FMA chain -> independent shuffle
// reductions) so only the 16-FMA chain is serial.
// ---------------------------------------------------------------------------
__global__ __launch_bounds__(512, 4) void scan_kernel(
    const float* __restrict__ xdbc,   // (BL, 48): [dt | B | C]
    const float* __restrict__ delta,  // (BL, 512)
    const float* __restrict__ u,      // (BL, 512)
    const float* __restrict__ xz,     // (BL, 1024); z at +512
    const float* __restrict__ A_log,  // (512, 16)
    const float* __restrict__ Dv,     // (512)
    float* __restrict__ y)            // (BL, 512)
{
    constexpr int TC = 64;   // timesteps per wave-chunk
    constexpr int SC = 16;   // register sub-chunk

    int blk  = blockIdx.x;           // 512 blocks: b*128 + dg
    int b    = blk >> 7;
    int dg   = blk & 127;
    int wave = threadIdx.x >> 6;     // 0..7 = time chunk id
    int lane = threadIdx.x & 63;
    int d    = dg * 4 + (lane >> 4);
    int n    = lane & 15;

    __shared__ float lds_Ap[8][64];
    __shared__ float lds_he[8][64];

    float Adn = -__expf(A_log[d * D_STATE + n]);
    float Dd  = Dv[d];
    size_t base = (size_t)b * L_SZ + (size_t)wave * TC;

    // ---- pass 1: local scan with h0 = 0; track decay product ----
    float h = 0.f, Ap = 1.f;
    for (int t0 = 0; t0 < TC; t0 += SC) {
        float dA[SC], dBu[SC];
        #pragma unroll
        for (int j = 0; j < SC; ++j) {
            size_t row = base + t0 + j;
            float Bv = xdbc[row * 48 + DT_RANK + n];
            float dl = delta[row * D_INNER + d];
            float uv = u[row * D_INNER + d];
            dA[j]  = __expf(dl * Adn);
            dBu[j] = dl * uv * Bv;
        }
        #pragma unroll
        for (int j = 0; j < SC; ++j) {
            h = dA[j] * h + dBu[j];
            Ap *= dA[j];
        }
    }
    lds_Ap[wave][lane] = Ap;
    lds_he[wave][lane] = h;
    __syncthreads();

    // ---- combine: state entering this wave's chunk ----
    float H = 0.f;
    for (int j = 0; j < wave; ++j)
        H = lds_Ap[j][lane] * H + lds_he[j][lane];

    // ---- pass 2: re-run chunk from H, emit y ----
    h = H;
    for (int t0 = 0; t0 < TC; t0 += SC) {
        float dA[SC], dBu[SC], Cv[SC], py[SC];
        #pragma unroll
        for (int j = 0; j < SC; ++j) {
            size_t row = base + t0 + j;
            float Bv = xdbc[row * 48 + DT_RANK + n];
            Cv[j]    = xdbc[row * 48 + DT_RANK + D_STATE + n];
            float dl = delta[row * D_INNER + d];
            float uv = u[row * D_INNER + d];
            dA[j]  = __expf(dl * Adn);
            dBu[j] = dl * uv * Bv;
        }
        #pragma unroll
        for (int j = 0; j < SC; ++j) {
            h = dA[j] * h + dBu[j];
            py[j] = h * Cv[j];
        }
        #pragma unroll
        for (int j = 0; j < SC; ++j) {
            float s = py[j];
            s += __shfl_xor(s, 8);
            s += __shfl_xor(s, 4);
            s += __shfl_xor(s, 2);
            s += __shfl_xor(s, 1);
            py[j] = s;
        }
        if (n == 0) {
            #pragma unroll
            for (int j = 0; j < SC; ++j) {
                size_t row = base + t0 + j;
                float uv = u[row * D_INNER + d];
                float zv = xz[row * (2 * D_INNER) + D_INNER + d];
                float sz = zv / (1.f + __expf(-zv));
                y[row * D_INNER + d] = (py[j] + uv * Dd) * sz;
            }
        }
    }
}

// ---------------------------------------------------------------------------
extern "C" void kernel_launch(void* const* d_in, const int* in_sizes, int n_in,
                              void* d_out, int out_size, void* d_ws, size_t ws_size,
                              hipStream_t stream)
{
    const float* x_in   = (const float*)d_in[0];
    const float* norm_w = (const float*)d_in[1];
    const float* W_in   = (const float*)d_in[2];
    const float* b_in   = (const float*)d_in[3];
    const float* conv_w = (const float*)d_in[4];
    const float* W_x    = (const float*)d_in[5];
    const float* dt_w   = (const float*)d_in[6];
    const float* dt_b   = (const float*)d_in[7];
    const float* A_log  = (const float*)d_in[8];
    const float* Dv     = (const float*)d_in[9];
    const float* W_out  = (const float*)d_in[10];
    const float* b_out  = (const float*)d_in[11];
    float* out = (float*)d_out;

    float* ws    = (float*)d_ws;
    float* xn    = ws;                      // 2048*256
    float* xz    = xn    + BL * D_MODEL;    // 2048*1024
    float* u     = xz    + BL * 2 * D_INNER;// 2048*512
    float* xdbc  = u     + BL * D_INNER;    // 2048*48
    float* delta = xdbc  + BL * 48;         // 2048*512
    float* y     = delta + BL * D_INNER;    // 2048*512

    for (int i = 0; i < N_LAYERS; ++i) {
        const float* xcur = (i == 0) ? x_in : out;

        rmsnorm_kernel<<<BL / 4, 256, 0, stream>>>(xcur, norm_w + i * D_MODEL, xn);

        // xz = xn @ W_in^T + b_in   (M=2048, N=1024, K=256)
        gemm_nt<64, 64, 16, 4, 4, 0><<<dim3(16, 32), 256, 0, stream>>>(
            xn, D_MODEL, W_in + (size_t)i * 2 * D_INNER * D_MODEL, D_MODEL,
            b_in + i * 2 * D_INNER, nullptr, 0, xz, 2 * D_INNER,
            BL, 2 * D_INNER, D_MODEL);

        conv_silu_kernel<<<BL * D_INNER / 256, 256, 0, stream>>>(
            xz, conv_w + i * D_INNER * 4, u);

        // xdbc = u @ W_x^T          (M=2048, N=48, K=512)
        gemm_nt<64, 16, 16, 4, 1, 0><<<dim3(3, 32), 256, 0, stream>>>(
            u, D_INNER, W_x + (size_t)i * 48 * D_INNER, D_INNER,
            nullptr, nullptr, 0, xdbc, 48,
            BL, 48, D_INNER);

        // delta = softplus(dt @ dt_w^T + dt_b)  (M=2048, N=512, K=16)
        gemm_nt<64, 64, 16, 4, 4, 1><<<dim3(8, 32), 256, 0, stream>>>(
            xdbc, 48, dt_w + (size_t)i * D_INNER * DT_RANK, DT_RANK,
            dt_b + i * D_INNER, nullptr, 0, delta, D_INNER,
            BL, D_INNER, DT_RANK);

        scan_kernel<<<512, 512, 0, stream>>>(
            xdbc, delta, u, xz,
            A_log + (size_t)i * D_INNER * D_STATE, Dv + i * D_INNER, y);

        // out = xcur + y @ W_out^T + b_out  (M=2048, N=256, K=512)
        gemm_nt<64, 64, 16, 4, 4, 0><<<dim3(4, 32), 256, 0, stream>>>(
            y, D_INNER, W_out + (size_t)i * D_MODEL * D_INNER, D_INNER,
            b_out + i * D_MODEL, xcur, D_MODEL, out, D_MODEL,
            BL, D_MODEL, D_INNER);
    }
}

// Round 4
// 617.225 us; speedup vs baseline: 4.5594x; 1.5080x over previous
//
#include <hip/hip_runtime.h>
#include <hip/hip_bf16.h>

#define B_SZ 4
#define L_SZ 512
#define D_MODEL 256
#define D_INNER 512
#define D_STATE 16
#define DT_RANK 16
#define N_LAYERS 6
#define BL (B_SZ * L_SZ)   // 2048 token rows

typedef __bf16 bf16_t;
typedef __bf16 bf16x8 __attribute__((ext_vector_type(8)));
typedef __bf16 bf16x4 __attribute__((ext_vector_type(4)));
typedef float  f32x4  __attribute__((ext_vector_type(4)));

// ---------------------------------------------------------------------------
// fp32 -> bf16 cast (weights), 4 elems/thread
// ---------------------------------------------------------------------------
__global__ __launch_bounds__(256) void cast_bf16_kernel(
    const float* __restrict__ src, bf16_t* __restrict__ dst, int n4)
{
    int i = blockIdx.x * 256 + threadIdx.x;
    if (i >= n4) return;
    const float4 v = *(const float4*)(src + i * 4);
    bf16x4 o;
    o[0] = (bf16_t)v.x; o[1] = (bf16_t)v.y;
    o[2] = (bf16_t)v.z; o[3] = (bf16_t)v.w;
    *(bf16x4*)(dst + i * 4) = o;
}

// ---------------------------------------------------------------------------
// RMSNorm -> bf16 output. One wave per row of 256; 4 rows per block.
// ---------------------------------------------------------------------------
__global__ __launch_bounds__(256) void rmsnorm_kernel(
    const float* __restrict__ x, const float* __restrict__ w,
    bf16_t* __restrict__ o)
{
    int row  = blockIdx.x * 4 + (threadIdx.x >> 6);
    int lane = threadIdx.x & 63;
    const float4 v = *(const float4*)(x + (size_t)row * D_MODEL + lane * 4);
    float ss = v.x * v.x + v.y * v.y + v.z * v.z + v.w * v.w;
    #pragma unroll
    for (int off = 32; off; off >>= 1) ss += __shfl_xor(ss, off);
    float rs = rsqrtf(ss * (1.f / D_MODEL) + 1e-5f);
    const float4 wv = *(const float4*)(w + lane * 4);
    bf16x4 ov;
    ov[0] = (bf16_t)(v.x * rs * wv.x);
    ov[1] = (bf16_t)(v.y * rs * wv.y);
    ov[2] = (bf16_t)(v.z * rs * wv.z);
    ov[3] = (bf16_t)(v.w * rs * wv.w);
    *(bf16x4*)(o + (size_t)row * D_MODEL + lane * 4) = ov;
}

// ---------------------------------------------------------------------------
// bf16 MFMA NT GEMM: C[M,N] = A[M,K] @ B[N,K]^T (+bias) (+residual), fp32 out.
// Wave grid WM x WN; each wave computes TM_T x TN_T tiles of 16x16.
// BK=64. Requires M%BM==0, N%BN==0, K%64==0.
// Fragment layouts (verified learn_hip m89/m91):
//   A/B frag: elem j of lane l -> [l&15][(l>>4)*8 + j]
//   C/D:      reg r of lane l -> row=(l>>4)*4+r, col=l&15
// ---------------------------------------------------------------------------
template<int WM, int WN, int TM_T, int TN_T, int HAS_BIAS, int HAS_RES>
__global__ __launch_bounds__(64 * WM * WN) void gemm_mfma_nt(
    const bf16_t* __restrict__ A, int lda,
    const bf16_t* __restrict__ Bw, int ldb,
    const float* __restrict__ bias,
    const float* __restrict__ R, int ldr,
    float* __restrict__ C, int ldc, int K)
{
    constexpr int BK = 64;
    constexpr int BM = WM * TM_T * 16;
    constexpr int BN = WN * TN_T * 16;
    constexpr int NT = 64 * WM * WN;
    constexpr int LDK = BK + 8;          // +16B pad: rows 16B-aligned
    __shared__ bf16_t As[BM][LDK];
    __shared__ bf16_t Bs[BN][LDK];

    const int tid  = threadIdx.x;
    const int wave = tid >> 6, lane = tid & 63;
    const int wm = wave / WN, wn = wave % WN;
    const int lm = lane & 15, quad = lane >> 4;
    const int m0 = blockIdx.y * BM, n0 = blockIdx.x * BN;

    f32x4 acc[TM_T][TN_T] = {};

    for (int k0 = 0; k0 < K; k0 += BK) {
        // stage A: BM*BK/8 16B chunks
        #pragma unroll
        for (int i = tid; i < BM * (BK / 8); i += NT) {
            int r = i >> 3, c8 = i & 7;
            *(bf16x8*)&As[r][c8 * 8] =
                *(const bf16x8*)(A + (size_t)(m0 + r) * lda + k0 + c8 * 8);
        }
        #pragma unroll
        for (int i = tid; i < BN * (BK / 8); i += NT) {
            int r = i >> 3, c8 = i & 7;
            *(bf16x8*)&Bs[r][c8 * 8] =
                *(const bf16x8*)(Bw + (size_t)(n0 + r) * ldb + k0 + c8 * 8);
        }
        __syncthreads();
        #pragma unroll
        for (int ks = 0; ks < BK / 32; ++ks) {
            bf16x8 af[TM_T], bfr[TN_T];
            #pragma unroll
            for (int i = 0; i < TM_T; ++i)
                af[i] = *(const bf16x8*)&As[wm * TM_T * 16 + i * 16 + lm][ks * 32 + quad * 8];
            #pragma unroll
            for (int j = 0; j < TN_T; ++j)
                bfr[j] = *(const bf16x8*)&Bs[wn * TN_T * 16 + j * 16 + lm][ks * 32 + quad * 8];
            #pragma unroll
            for (int i = 0; i < TM_T; ++i)
                #pragma unroll
                for (int j = 0; j < TN_T; ++j)
                    acc[i][j] = __builtin_amdgcn_mfma_f32_16x16x32_bf16(
                        af[i], bfr[j], acc[i][j], 0, 0, 0);
        }
        __syncthreads();
    }

    #pragma unroll
    for (int i = 0; i < TM_T; ++i) {
        #pragma unroll
        for (int j = 0; j < TN_T; ++j) {
            int col = n0 + wn * TN_T * 16 + j * 16 + lm;
            #pragma unroll
            for (int r = 0; r < 4; ++r) {
                int rowm = m0 + wm * TM_T * 16 + i * 16 + quad * 4 + r;
                float v = acc[i][j][r];
                if (HAS_BIAS) v += bias[col];
                if (HAS_RES)  v += R[(size_t)rowm * ldr + col];
                C[(size_t)rowm * ldc + col] = v;
            }
        }
    }
}

// ---------------------------------------------------------------------------
// fp32 VALU NT GEMM (kept for delta: K=16, + softplus epilogue)
// ---------------------------------------------------------------------------
template<int BM, int BN, int BK, int TM, int TN, int ACT>
__global__ __launch_bounds__(256) void gemm_nt(
    const float* __restrict__ A, int lda,
    const float* __restrict__ Bm, int ldb,
    const float* __restrict__ bias,
    float* __restrict__ C, int ldc,
    int M, int N, int K)
{
    __shared__ float As[BK][BM + 4];
    __shared__ float Bs[BK][BN + 4];
    constexpr int TX = BN / TN;
    constexpr int TY = BM / TM;
    static_assert(TX * TY == 256, "thread layout");
    const int tid = threadIdx.x;
    const int tx = tid % TX, ty = tid / TX;
    const int m0 = blockIdx.y * BM, n0 = blockIdx.x * BN;

    float acc[TM][TN] = {};

    for (int k0 = 0; k0 < K; k0 += BK) {
        constexpr int AV = BM * BK / 4;
        #pragma unroll
        for (int idx = tid; idx < AV; idx += 256) {
            int r = idx / (BK / 4);
            int c = (idx % (BK / 4)) * 4;
            float4 v = *(const float4*)(A + (size_t)(m0 + r) * lda + k0 + c);
            As[c + 0][r] = v.x; As[c + 1][r] = v.y;
            As[c + 2][r] = v.z; As[c + 3][r] = v.w;
        }
        constexpr int BV = BN * BK / 4;
        #pragma unroll
        for (int idx = tid; idx < BV; idx += 256) {
            int r = idx / (BK / 4);
            int c = (idx % (BK / 4)) * 4;
            float4 v = *(const float4*)(Bm + (size_t)(n0 + r) * ldb + k0 + c);
            Bs[c + 0][r] = v.x; Bs[c + 1][r] = v.y;
            Bs[c + 2][r] = v.z; Bs[c + 3][r] = v.w;
        }
        __syncthreads();
        #pragma unroll
        for (int k = 0; k < BK; ++k) {
            float am[TM], bn[TN];
            #pragma unroll
            for (int i = 0; i < TM; i++) am[i] = As[k][ty * TM + i];
            #pragma unroll
            for (int j = 0; j < TN; j++) bn[j] = Bs[k][tx * TN + j];
            #pragma unroll
            for (int i = 0; i < TM; i++)
                #pragma unroll
                for (int j = 0; j < TN; j++)
                    acc[i][j] += am[i] * bn[j];
        }
        __syncthreads();
    }

    #pragma unroll
    for (int i = 0; i < TM; i++) {
        int m = m0 + ty * TM + i;
        #pragma unroll
        for (int j = 0; j < TN; j++) {
            int n = n0 + tx * TN + j;
            float v = acc[i][j];
            if (bias) v += bias[n];
            if (ACT == 1) v = (v > 20.f) ? v : log1pf(__expf(v));
            C[(size_t)m * ldc + n] = v;
        }
    }
}

// ---------------------------------------------------------------------------
// Depthwise causal conv (width 4) + SiLU -> u (fp32) and ub (bf16)
// ---------------------------------------------------------------------------
__global__ __launch_bounds__(256) void conv_silu_kernel(
    const float* __restrict__ xz, const float* __restrict__ cw,
    float* __restrict__ u, bf16_t* __restrict__ ub)
{
    int idx = blockIdx.x * 256 + threadIdx.x;   // (b*L + t)*512 + d
    int d  = idx & (D_INNER - 1);
    int bt = idx >> 9;
    int t  = bt & (L_SZ - 1);
    const float4 wv = *(const float4*)(cw + d * 4);
    const float* base = xz + (size_t)bt * (2 * D_INNER) + d;
    float acc = wv.w * base[0];
    if (t >= 1) acc += wv.z * base[-(2 * D_INNER)];
    if (t >= 2) acc += wv.y * base[-(4 * D_INNER)];
    if (t >= 3) acc += wv.x * base[-(6 * D_INNER)];
    float s = acc / (1.f + __expf(-acc));
    u[idx]  = s;
    ub[idx] = (bf16_t)s;
}

// ---------------------------------------------------------------------------
// Selective scan, time-parallel block-chunked (see round 3). y -> bf16.
// ---------------------------------------------------------------------------
__global__ __launch_bounds__(512, 4) void scan_kernel(
    const float* __restrict__ xdbc,   // (BL, 48): [dt | B | C]
    const float* __restrict__ delta,  // (BL, 512)
    const float* __restrict__ u,      // (BL, 512)
    const float* __restrict__ xz,     // (BL, 1024); z at +512
    const float* __restrict__ A_log,  // (512, 16)
    const float* __restrict__ Dv,     // (512)
    bf16_t* __restrict__ y)           // (BL, 512) bf16
{
    constexpr int TC = 64;
    constexpr int SC = 16;

    int blk  = blockIdx.x;           // 512 blocks: b*128 + dg
    int b    = blk >> 7;
    int dg   = blk & 127;
    int wave = threadIdx.x >> 6;     // time chunk id
    int lane = threadIdx.x & 63;
    int d    = dg * 4 + (lane >> 4);
    int n    = lane & 15;

    __shared__ float lds_Ap[8][64];
    __shared__ float lds_he[8][64];

    float Adn = -__expf(A_log[d * D_STATE + n]);
    float Dd  = Dv[d];
    size_t base = (size_t)b * L_SZ + (size_t)wave * TC;

    float h = 0.f, Ap = 1.f;
    for (int t0 = 0; t0 < TC; t0 += SC) {
        float dA[SC], dBu[SC];
        #pragma unroll
        for (int j = 0; j < SC; ++j) {
            size_t row = base + t0 + j;
            float Bv = xdbc[row * 48 + DT_RANK + n];
            float dl = delta[row * D_INNER + d];
            float uv = u[row * D_INNER + d];
            dA[j]  = __expf(dl * Adn);
            dBu[j] = dl * uv * Bv;
        }
        #pragma unroll
        for (int j = 0; j < SC; ++j) {
            h = dA[j] * h + dBu[j];
            Ap *= dA[j];
        }
    }
    lds_Ap[wave][lane] = Ap;
    lds_he[wave][lane] = h;
    __syncthreads();

    float H = 0.f;
    for (int j = 0; j < wave; ++j)
        H = lds_Ap[j][lane] * H + lds_he[j][lane];

    h = H;
    for (int t0 = 0; t0 < TC; t0 += SC) {
        float dA[SC], dBu[SC], Cv[SC], py[SC];
        #pragma unroll
        for (int j = 0; j < SC; ++j) {
            size_t row = base + t0 + j;
            float Bv = xdbc[row * 48 + DT_RANK + n];
            Cv[j]    = xdbc[row * 48 + DT_RANK + D_STATE + n];
            float dl = delta[row * D_INNER + d];
            float uv = u[row * D_INNER + d];
            dA[j]  = __expf(dl * Adn);
            dBu[j] = dl * uv * Bv;
        }
        #pragma unroll
        for (int j = 0; j < SC; ++j) {
            h = dA[j] * h + dBu[j];
            py[j] = h * Cv[j];
        }
        #pragma unroll
        for (int j = 0; j < SC; ++j) {
            float s = py[j];
            s += __shfl_xor(s, 8);
            s += __shfl_xor(s, 4);
            s += __shfl_xor(s, 2);
            s += __shfl_xor(s, 1);
            py[j] = s;
        }
        if (n == 0) {
            #pragma unroll
            for (int j = 0; j < SC; ++j) {
                size_t row = base + t0 + j;
                float uv = u[row * D_INNER + d];
                float zv = xz[row * (2 * D_INNER) + D_INNER + d];
                float sz = zv / (1.f + __expf(-zv));
                y[row * D_INNER + d] = (bf16_t)((py[j] + uv * Dd) * sz);
            }
        }
    }
}

// ---------------------------------------------------------------------------
extern "C" void kernel_launch(void* const* d_in, const int* in_sizes, int n_in,
                              void* d_out, int out_size, void* d_ws, size_t ws_size,
                              hipStream_t stream)
{
    const float* x_in   = (const float*)d_in[0];
    const float* norm_w = (const float*)d_in[1];
    const float* W_in   = (const float*)d_in[2];
    const float* b_in   = (const float*)d_in[3];
    const float* conv_w = (const float*)d_in[4];
    const float* W_x    = (const float*)d_in[5];
    const float* dt_w   = (const float*)d_in[6];
    const float* dt_b   = (const float*)d_in[7];
    const float* A_log  = (const float*)d_in[8];
    const float* Dv     = (const float*)d_in[9];
    const float* W_out  = (const float*)d_in[10];
    const float* b_out  = (const float*)d_in[11];
    float* out = (float*)d_out;

    // fp32 scratch
    float* ws    = (float*)d_ws;
    float* xz    = ws;                       // 2048*1024
    float* u     = xz    + BL * 2 * D_INNER; // 2048*512
    float* xdbc  = u     + BL * D_INNER;     // 2048*48
    float* delta = xdbc  + BL * 48;          // 2048*512
    // bf16 scratch
    bf16_t* bws   = (bf16_t*)(delta + BL * D_INNER);
    bf16_t* xn_bf = bws;                     // 2048*256
    bf16_t* ub    = xn_bf + BL * D_MODEL;    // 2048*512
    bf16_t* y_bf  = ub    + BL * D_INNER;    // 2048*512
    bf16_t* Wi_bf = y_bf  + BL * D_INNER;    // 6*1024*256
    bf16_t* Wx_bf = Wi_bf + N_LAYERS * 2 * D_INNER * D_MODEL;  // 6*48*512
    bf16_t* Wo_bf = Wx_bf + N_LAYERS * (DT_RANK + 2 * D_STATE) * D_INNER; // 6*256*512

    // ---- one-time weight casts (rerun every call; same work each call) ----
    {
        int n4 = N_LAYERS * 2 * D_INNER * D_MODEL / 4;
        cast_bf16_kernel<<<(n4 + 255) / 256, 256, 0, stream>>>(W_in, Wi_bf, n4);
        n4 = N_LAYERS * 48 * D_INNER / 4;
        cast_bf16_kernel<<<(n4 + 255) / 256, 256, 0, stream>>>(W_x, Wx_bf, n4);
        n4 = N_LAYERS * D_MODEL * D_INNER / 4;
        cast_bf16_kernel<<<(n4 + 255) / 256, 256, 0, stream>>>(W_out, Wo_bf, n4);
    }

    for (int i = 0; i < N_LAYERS; ++i) {
        const float* xcur = (i == 0) ? x_in : out;

        rmsnorm_kernel<<<BL / 4, 256, 0, stream>>>(xcur, norm_w + i * D_MODEL, xn_bf);

        // xz = xn @ W_in^T + b_in   (M=2048, N=1024, K=256)
        gemm_mfma_nt<2, 2, 2, 2, 1, 0><<<dim3(1024 / 64, 2048 / 64), 256, 0, stream>>>(
            xn_bf, D_MODEL, Wi_bf + (size_t)i * 2 * D_INNER * D_MODEL, D_MODEL,
            b_in + i * 2 * D_INNER, nullptr, 0, xz, 2 * D_INNER, D_MODEL);

        conv_silu_kernel<<<BL * D_INNER / 256, 256, 0, stream>>>(
            xz, conv_w + i * D_INNER * 4, u, ub);

        // xdbc = u @ W_x^T          (M=2048, N=48, K=512)
        gemm_mfma_nt<4, 1, 1, 3, 0, 0><<<dim3(1, 2048 / 64), 256, 0, stream>>>(
            ub, D_INNER, Wx_bf + (size_t)i * 48 * D_INNER, D_INNER,
            nullptr, nullptr, 0, xdbc, 48, D_INNER);

        // delta = softplus(dt @ dt_w^T + dt_b)  (M=2048, N=512, K=16)
        gemm_nt<64, 64, 16, 4, 4, 1><<<dim3(8, 32), 256, 0, stream>>>(
            xdbc, 48, dt_w + (size_t)i * D_INNER * DT_RANK, DT_RANK,
            dt_b + i * D_INNER, delta, D_INNER,
            BL, D_INNER, DT_RANK);

        scan_kernel<<<512, 512, 0, stream>>>(
            xdbc, delta, u, xz,
            A_log + (size_t)i * D_INNER * D_STATE, Dv + i * D_INNER, y_bf);

        // out = xcur + y @ W_out^T + b_out  (M=2048, N=256, K=512)
        gemm_mfma_nt<2, 2, 2, 2, 1, 1><<<dim3(256 / 64, 2048 / 64), 256, 0, stream>>>(
            y_bf, D_INNER, Wo_bf + (size_t)i * D_MODEL * D_INNER, D_INNER,
            b_out + i * D_MODEL, xcur, D_MODEL, out, D_MODEL, D_INNER);
    }
}